// Round 1
// baseline (1305.853 us; speedup 1.0000x reference)
//
#include <hip/hip_runtime.h>
#include <cstdint>
#include <cstdio>

typedef unsigned short u16;
typedef unsigned int u32;
typedef __attribute__((ext_vector_type(8))) short short8;
typedef __attribute__((ext_vector_type(4))) float f32x4;

#define E_N 8
#define T_N 1024
#define D_N 2048
#define I_N 4096

// fp32 -> bf16 round-to-nearest-even (inputs are sane, no NaN handling)
__device__ __forceinline__ u16 f2bf(float f) {
  u32 u = __builtin_bit_cast(u32, f);
  u32 r = (u + 0x7FFFu + ((u >> 16) & 1u)) >> 16;
  return (u16)r;
}

// async global->LDS, 16B per lane; LDS dest = wave-uniform base + lane*16
__device__ __forceinline__ void g2l16(const void* g, void* l) {
  __builtin_amdgcn_global_load_lds(
      (const __attribute__((address_space(1))) void*)g,
      (__attribute__((address_space(3))) void*)l, 16, 0, 0);
}

// ---------------- prepass: x fp32 -> bf16, same layout ----------------
__global__ void cvt_x_kernel(const float4* __restrict__ in, uint2* __restrict__ out, int n4) {
  int i = blockIdx.x * blockDim.x + threadIdx.x;
  if (i >= n4) return;
  float4 v = in[i];
  uint2 p;
  p.x = (u32)f2bf(v.x) | ((u32)f2bf(v.y) << 16);
  p.y = (u32)f2bf(v.z) | ((u32)f2bf(v.w) << 16);
  out[i] = p;
}

// ---- prepass: per-expert (R,C) fp32 -> (C,R) bf16 (convert + transpose) ----
__global__ void tr_cvt_kernel(const float* __restrict__ in, u16* __restrict__ out,
                              int R, int C) {
  __shared__ u16 tile[64][66];  // [c-within-tile][r-within-tile], pad keeps 4B align + 2-way-max banks
  int e = blockIdx.z;
  const float* ine = in + (size_t)e * R * C;
  u16* oute = out + (size_t)e * R * C;
  int c0 = blockIdx.x * 64, r0 = blockIdx.y * 64;
  int tid = threadIdx.x;
  int tx = tid & 63, ty = tid >> 6;
#pragma unroll
  for (int rr = ty; rr < 64; rr += 4)
    tile[tx][rr] = f2bf(ine[(size_t)(r0 + rr) * C + c0 + tx]);
  __syncthreads();
  int tx2 = tid & 31, ty2 = tid >> 5;
#pragma unroll
  for (int cc = ty2; cc < 64; cc += 8) {
    u32 v = *(const u32*)&tile[cc][2 * tx2];
    *(u32*)&oute[(size_t)(c0 + cc) * R + r0 + 2 * tx2] = v;
  }
}

// ------- fused GEMM1+2: h = silu(x@gp) * (x@ip), bf16 out, per expert -------
// xb: (E,T,D) bf16 row-major (K=D contiguous)  -> A operand
// gT/iT: (E,I,D) bf16 (N-major, K contiguous)  -> B operands
// hb: (E,T,I) bf16
__global__ __launch_bounds__(256, 2) void gemm12_kernel(
    const u16* __restrict__ xb, const u16* __restrict__ gT,
    const u16* __restrict__ iT, u16* __restrict__ hb) {
  __shared__ __align__(16) u16 As[128 * 32];
  __shared__ __align__(16) u16 Bg[128 * 32];
  __shared__ __align__(16) u16 Bi[128 * 32];

  const int TM = T_N / 128;  // 8
  const int TN = I_N / 128;  // 32
  int bid = blockIdx.x;
  int e = bid / (TM * TN);
  int r = bid % (TM * TN);
  int tm = r / TN;
  int tn = r % TN;

  const u16* xe = xb + ((size_t)e * T_N + (size_t)tm * 128) * D_N;
  const u16* ge = gT + ((size_t)e * I_N + (size_t)tn * 128) * D_N;
  const u16* ie = iT + ((size_t)e * I_N + (size_t)tn * 128) * D_N;

  int tid = threadIdx.x;
  int lane = tid & 63;
  int wid = tid >> 6;          // 4 waves: 2x2 over the 128x128 tile
  int wm = wid & 1, wn = wid >> 1;

  int crow = lane >> 2;        // row within a 16-row staging chunk
  int kcol = (lane & 3) << 3;  // 0,8,16,24 (bf16 elems; 16B per lane)
  int fr = lane & 15;
  int quad = lane >> 4;

  f32x4 accg[4][4], acci[4][4];
#pragma unroll
  for (int i = 0; i < 4; ++i)
#pragma unroll
    for (int j = 0; j < 4; ++j) {
      accg[i][j] = {0.f, 0.f, 0.f, 0.f};
      acci[i][j] = {0.f, 0.f, 0.f, 0.f};
    }

  for (int k0 = 0; k0 < D_N; k0 += 32) {
    __syncthreads();
#pragma unroll
    for (int c = 0; c < 2; ++c) {
      int chunk = wid * 2 + c;                  // wave-uniform
      int row = chunk * 16 + crow;
      size_t goff = (size_t)row * D_N + k0 + kcol;
      g2l16(xe + goff, (char*)As + chunk * 1024);
      g2l16(ge + goff, (char*)Bg + chunk * 1024);
      g2l16(ie + goff, (char*)Bi + chunk * 1024);
    }
    __syncthreads();  // compiler drains vmcnt(0) before s_barrier

    short8 a[4], bg[4], bi[4];
#pragma unroll
    for (int mi = 0; mi < 4; ++mi)
      a[mi] = *(const short8*)&As[(wm * 64 + mi * 16 + fr) * 32 + quad * 8];
#pragma unroll
    for (int ni = 0; ni < 4; ++ni) {
      bg[ni] = *(const short8*)&Bg[(wn * 64 + ni * 16 + fr) * 32 + quad * 8];
      bi[ni] = *(const short8*)&Bi[(wn * 64 + ni * 16 + fr) * 32 + quad * 8];
    }
#pragma unroll
    for (int mi = 0; mi < 4; ++mi)
#pragma unroll
      for (int ni = 0; ni < 4; ++ni) {
        accg[mi][ni] = __builtin_amdgcn_mfma_f32_16x16x32_bf16(a[mi], bg[ni], accg[mi][ni], 0, 0, 0);
        acci[mi][ni] = __builtin_amdgcn_mfma_f32_16x16x32_bf16(a[mi], bi[ni], acci[mi][ni], 0, 0, 0);
      }
  }

  // epilogue: silu(g)*u -> bf16 h.  C/D layout: col=lane&15, row=quad*4+reg
  u16* he = hb + (size_t)e * T_N * I_N;
  int orow0 = tm * 128 + wm * 64 + quad * 4;
  int ocol0 = tn * 128 + wn * 64 + fr;
#pragma unroll
  for (int mi = 0; mi < 4; ++mi)
#pragma unroll
    for (int ni = 0; ni < 4; ++ni)
#pragma unroll
      for (int rg = 0; rg < 4; ++rg) {
        float g = accg[mi][ni][rg];
        float u = acci[mi][ni][rg];
        float s = g / (1.0f + __expf(-g));  // g->-inf: exp->inf, s->-0  (correct)
        int row = orow0 + mi * 16 + rg;
        int col = ocol0 + ni * 16;
        he[(size_t)row * I_N + col] = f2bf(s * u);
      }
}

// ---------------- GEMM3: out = h @ op, fp32 out, per expert ----------------
// hb: (E,T,I) bf16 (K=I contiguous), oT: (E,D,I) bf16 (N-major, K contiguous)
__global__ __launch_bounds__(256, 2) void gemm3_kernel(
    const u16* __restrict__ hb, const u16* __restrict__ oT, float* __restrict__ out) {
  __shared__ __align__(16) u16 As[128 * 32];
  __shared__ __align__(16) u16 Bs[128 * 32];

  const int TM = T_N / 128;  // 8
  const int TN = D_N / 128;  // 16
  int bid = blockIdx.x;
  int e = bid / (TM * TN);
  int r = bid % (TM * TN);
  int tm = r / TN;
  int tn = r % TN;

  const u16* ae = hb + ((size_t)e * T_N + (size_t)tm * 128) * I_N;
  const u16* be = oT + ((size_t)e * D_N + (size_t)tn * 128) * I_N;

  int tid = threadIdx.x;
  int lane = tid & 63;
  int wid = tid >> 6;
  int wm = wid & 1, wn = wid >> 1;
  int crow = lane >> 2;
  int kcol = (lane & 3) << 3;
  int fr = lane & 15;
  int quad = lane >> 4;

  f32x4 acc[4][4];
#pragma unroll
  for (int i = 0; i < 4; ++i)
#pragma unroll
    for (int j = 0; j < 4; ++j) acc[i][j] = {0.f, 0.f, 0.f, 0.f};

  for (int k0 = 0; k0 < I_N; k0 += 32) {
    __syncthreads();
#pragma unroll
    for (int c = 0; c < 2; ++c) {
      int chunk = wid * 2 + c;
      int row = chunk * 16 + crow;
      size_t goff = (size_t)row * I_N + k0 + kcol;
      g2l16(ae + goff, (char*)As + chunk * 1024);
      g2l16(be + goff, (char*)Bs + chunk * 1024);
    }
    __syncthreads();

    short8 a[4], b[4];
#pragma unroll
    for (int mi = 0; mi < 4; ++mi)
      a[mi] = *(const short8*)&As[(wm * 64 + mi * 16 + fr) * 32 + quad * 8];
#pragma unroll
    for (int ni = 0; ni < 4; ++ni)
      b[ni] = *(const short8*)&Bs[(wn * 64 + ni * 16 + fr) * 32 + quad * 8];
#pragma unroll
    for (int mi = 0; mi < 4; ++mi)
#pragma unroll
      for (int ni = 0; ni < 4; ++ni)
        acc[mi][ni] = __builtin_amdgcn_mfma_f32_16x16x32_bf16(a[mi], b[ni], acc[mi][ni], 0, 0, 0);
  }

  float* oe = out + (size_t)e * T_N * D_N;
  int orow0 = tm * 128 + wm * 64 + quad * 4;
  int ocol0 = tn * 128 + wn * 64 + fr;
#pragma unroll
  for (int mi = 0; mi < 4; ++mi)
#pragma unroll
    for (int ni = 0; ni < 4; ++ni)
#pragma unroll
      for (int rg = 0; rg < 4; ++rg) {
        int row = orow0 + mi * 16 + rg;
        int col = ocol0 + ni * 16;
        oe[(size_t)row * D_N + col] = acc[mi][ni][rg];
      }
}

extern "C" void kernel_launch(void* const* d_in, const int* in_sizes, int n_in,
                              void* d_out, int out_size, void* d_ws, size_t ws_size,
                              hipStream_t stream) {
  const float* x = (const float*)d_in[0];
  const float* gp = (const float*)d_in[1];
  const float* ip = (const float*)d_in[2];
  const float* op = (const float*)d_in[3];
  float* out = (float*)d_out;

  const size_t szX = (size_t)E_N * T_N * D_N * 2;  // bf16 x
  const size_t szW = (size_t)E_N * D_N * I_N * 2;  // each bf16 weight (transposed)
  const size_t szH = (size_t)E_N * T_N * I_N * 2;  // bf16 h
  const size_t need = szX + 3 * szW + szH;         // 480 MiB
  if (ws_size < need) {
    fprintf(stderr, "kernel_launch: ws_size %zu < needed %zu\n", ws_size, need);
    return;
  }

  char* w = (char*)d_ws;
  u16* xb = (u16*)w; w += szX;
  u16* gT = (u16*)w; w += szW;
  u16* iT = (u16*)w; w += szW;
  u16* oTt = (u16*)w; w += szW;
  u16* hb = (u16*)w; w += szH;

  // prepass
  int n4 = E_N * T_N * D_N / 4;
  cvt_x_kernel<<<(n4 + 255) / 256, 256, 0, stream>>>((const float4*)x, (uint2*)xb, n4);
  dim3 tg1(I_N / 64, D_N / 64, E_N);  // gate/inner: (D,I) -> (I,D)
  tr_cvt_kernel<<<tg1, 256, 0, stream>>>(gp, gT, D_N, I_N);
  tr_cvt_kernel<<<tg1, 256, 0, stream>>>(ip, iT, D_N, I_N);
  dim3 tg2(D_N / 64, I_N / 64, E_N);  // op: (I,D) -> (D,I)
  tr_cvt_kernel<<<tg2, 256, 0, stream>>>(op, oTt, I_N, D_N);

  // fused GEMM1+2 -> h (bf16)
  gemm12_kernel<<<E_N * (T_N / 128) * (I_N / 128), 256, 0, stream>>>(xb, gT, iT, hb);
  // GEMM3 -> out (fp32)
  gemm3_kernel<<<E_N * (T_N / 128) * (D_N / 128), 256, 0, stream>>>(hb, oTt, out);
}